// Round 9
// baseline (43.929 us; speedup 1.0000x reference)
//
#include <hip/hip_runtime.h>

// B=2048, N=8192, F=512, H=8, F_=64
// Identity: softmax_n(e1[b]+e2[n]) == softmax_n(e2[n]) => output independent of b.
// Deferred normalization (softmax shift-invariant; e2 ~ N(0,0.45), exp safe):
//   w2[h] = W[h]@a2[h];  g[h] = sum_n exp(G[n].w2[h]) G[n];  s[h] = sum_n exp(...)
//   out[b,:] = relu((g[h]/s[h]) @ W[h])   broadcast over b.
//
// Round-8 lesson: the ~30us stall was the SPIN, not the publish. Relaxed
// agent-scope atomic LOAD compiles to a cached load; the counter line sticks
// stale in the spinning XCD's L2 (memory-side RMWs from other XCDs don't
// invalidate it) until random eviction. Fix: poll with fetch_add(0) — an RMW
// always executes at the coherent point and returns fresh data, no fences,
// no invalidates. Publish stays pure atomic STORES (no RMW data atomics);
// phase B reads partials with relaxed agent atomic loads (first-touched only
// after the sync => never stale).

#define HF   8
#define FDIM 512
#define FE   64
#define NG   8192
#define BX   2048
#define NBLK 128
#define NTHR 512
#define ROWSPB (NG / NBLK)    // 64 rows of G per block, 8 per wave

// ws float layout: [0]=counter (own 256B line) | [64..4160)=w2
//                  [4224..5248)=s_part[128][8] | [8192..8192+128*4096)=part
#define WS_W2   64
#define WS_SP   4224
#define WS_PART 8192

__global__ __launch_bounds__(256) void k_init(const float* __restrict__ W,
                                              const float* __restrict__ att,
                                              float* __restrict__ ws) {
    int bid = blockIdx.x, tid = threadIdx.x;
    if (bid == 0 && tid == 0)
        __hip_atomic_store(reinterpret_cast<unsigned int*>(ws), 0u,
                           __ATOMIC_RELAXED, __HIP_MEMORY_SCOPE_AGENT);

    // w2: 64 outputs per block, 4 threads per output (16 floats each)
    int o = bid * 64 + (tid >> 2);                 // 0..4095  (o = h*512 + f)
    int sub = tid & 3;
    int h = o >> 9;
    const float* wp = W + (size_t)o * FE + sub * 16;
    const float* a2 = att + h * (2 * FE) + FE + sub * 16;
    float s = 0.f;
#pragma unroll
    for (int e = 0; e < 16; e += 4) {
        float4 w4 = *reinterpret_cast<const float4*>(wp + e);
        s += w4.x * a2[e] + w4.y * a2[e + 1] + w4.z * a2[e + 2] + w4.w * a2[e + 3];
    }
    s += __shfl_xor(s, 1, 64);
    s += __shfl_xor(s, 2, 64);
    if (sub == 0) ws[WS_W2 + o] = s;
}

__global__ __launch_bounds__(NTHR, 1) void k_fused(const float* __restrict__ G,
                                                   const float* __restrict__ W,
                                                   float* __restrict__ ws,
                                                   float* __restrict__ out) {
    __shared__ float lds2[2][HF * FDIM];           // 32 KiB combine buffers
    __shared__ float s_lds[8][HF];
    __shared__ float gh[FDIM];
    __shared__ float vp[32][17];
    __shared__ float vrs[16];
    __shared__ float s_tmp[128];
    __shared__ float s_red[8];
    __shared__ float s_h_lds;

    int bid = blockIdx.x, tid = threadIdx.x;
    int wave = tid >> 6, lane = tid & 63;          // 8 waves
    const float* w2g = ws + WS_W2;
    float* s_part = ws + WS_SP;                    // [128][8]
    float* part   = ws + WS_PART;                  // [128][4096]
    unsigned int* counter = reinterpret_cast<unsigned int*>(ws);

    // ---------------- Phase A: G pass (partial g, s) ----------------
    float4 w2a[HF], w2b[HF];
#pragma unroll
    for (int h = 0; h < HF; ++h) {
        const float* wp = w2g + h * FDIM + lane * 8;
        w2a[h] = *reinterpret_cast<const float4*>(wp);
        w2b[h] = *reinterpret_cast<const float4*>(wp + 4);
    }
    float4 accA[HF], accB[HF];
#pragma unroll
    for (int h = 0; h < HF; ++h) {
        accA[h] = make_float4(0.f, 0.f, 0.f, 0.f);
        accB[h] = make_float4(0.f, 0.f, 0.f, 0.f);
    }
    float s_acc[HF] = {};

    int n0 = bid * ROWSPB + wave * (ROWSPB / 8);
    for (int r = 0; r < ROWSPB / 8; ++r) {
        const float* gp = G + (size_t)(n0 + r) * FDIM + lane * 8;
        float4 g0 = *reinterpret_cast<const float4*>(gp);
        float4 g1 = *reinterpret_cast<const float4*>(gp + 4);
        float e[HF];
#pragma unroll
        for (int h = 0; h < HF; ++h)
            e[h] = g0.x * w2a[h].x + g0.y * w2a[h].y + g0.z * w2a[h].z + g0.w * w2a[h].w
                 + g1.x * w2b[h].x + g1.y * w2b[h].y + g1.z * w2b[h].z + g1.w * w2b[h].w;
#pragma unroll
        for (int off = 32; off > 0; off >>= 1) {
#pragma unroll
            for (int h = 0; h < HF; ++h) e[h] += __shfl_xor(e[h], off, 64);
        }
#pragma unroll
        for (int h = 0; h < HF; ++h) {
            float w = __expf(e[h]);                // identical across lanes
            s_acc[h] += w;
            accA[h].x = fmaf(w, g0.x, accA[h].x);
            accA[h].y = fmaf(w, g0.y, accA[h].y);
            accA[h].z = fmaf(w, g0.z, accA[h].z);
            accA[h].w = fmaf(w, g0.w, accA[h].w);
            accB[h].x = fmaf(w, g1.x, accB[h].x);
            accB[h].y = fmaf(w, g1.y, accB[h].y);
            accB[h].z = fmaf(w, g1.z, accB[h].z);
            accB[h].w = fmaf(w, g1.w, accB[h].w);
        }
    }

    if (lane == 0) {
#pragma unroll
        for (int h = 0; h < HF; ++h) s_lds[wave][h] = s_acc[h];
    }

    // 8-wave combine into 2 LDS buffers (waves {0,1},{2,3},{4,5},{6,7} in order)
    for (int rnd = 0; rnd < 4; ++rnd) {
        if ((wave >> 1) == rnd) {
            int buf = wave & 1;
#pragma unroll
            for (int h = 0; h < HF; ++h) {
                float* dst = lds2[buf] + h * FDIM + lane * 8;
                if (rnd == 0) {
                    *reinterpret_cast<float4*>(dst)     = accA[h];
                    *reinterpret_cast<float4*>(dst + 4) = accB[h];
                } else {
                    float4 t0 = *reinterpret_cast<float4*>(dst);
                    float4 t1 = *reinterpret_cast<float4*>(dst + 4);
                    t0.x += accA[h].x; t0.y += accA[h].y; t0.z += accA[h].z; t0.w += accA[h].w;
                    t1.x += accB[h].x; t1.y += accB[h].y; t1.z += accB[h].z; t1.w += accB[h].w;
                    *reinterpret_cast<float4*>(dst)     = t0;
                    *reinterpret_cast<float4*>(dst + 4) = t1;
                }
            }
        }
        __syncthreads();
    }

    // publish per-block partial: pure atomic STORES to the coherent point
    {
        float* pdst = part + (size_t)bid * (HF * FDIM);
        for (int i = tid; i < HF * FDIM; i += NTHR)
            __hip_atomic_store(&pdst[i], lds2[0][i] + lds2[1][i],
                               __ATOMIC_RELAXED, __HIP_MEMORY_SCOPE_AGENT);
        if (tid < HF) {
            float sv = 0.f;
#pragma unroll
            for (int w = 0; w < 8; ++w) sv += s_lds[w][tid];
            __hip_atomic_store(&s_part[bid * HF + tid], sv,
                               __ATOMIC_RELAXED, __HIP_MEMORY_SCOPE_AGENT);
        }
    }

    // ---------------- spin-sync: RMW polls only (always fresh) ----------------
    // __syncthreads drains vmcnt(0) => this block's stores are at the
    // coherent point before the arrive. fetch_add(0) executes at the coherent
    // point => no stale-L2-line hazard (round-8 lesson), no fences needed.
    __syncthreads();
    if (tid == 0) {
        __hip_atomic_fetch_add(counter, 1u, __ATOMIC_RELAXED, __HIP_MEMORY_SCOPE_AGENT);
        int iters = 0;
        while (__hip_atomic_fetch_add(counter, 0u, __ATOMIC_RELAXED,
                                      __HIP_MEMORY_SCOPE_AGENT) < NBLK) {
            __builtin_amdgcn_s_sleep(8);
            if (++iters > 100000) break;           // escape hatch: fail, never hang
        }
    }
    __syncthreads();

    // ---------------- Phase B: reduce + vr slice + output write ----------------
    // 128 blocks = 32 column-slices (h, 16 e's) x 4 row-chunks of 512 rows
    int slice = bid & 31, rc = bid >> 5;
    int h = slice >> 2, e0 = (slice & 3) * 16;

    // gh[f] = sum over 128 partials (relaxed agent atomic loads; fixed order;
    // lines first touched after the sync => never stale)
    {
        float acc = 0.f;
        const float* pcol = part + (h << 9) + tid;   // tid = f (0..511)
#pragma unroll 8
        for (int p = 0; p < NBLK; ++p)
            acc += __hip_atomic_load(pcol + (size_t)p * (HF * FDIM),
                                     __ATOMIC_RELAXED, __HIP_MEMORY_SCOPE_AGENT);
        gh[tid] = acc;
    }
    if (tid < 128)
        s_tmp[tid] = __hip_atomic_load(&s_part[tid * HF + h],
                                       __ATOMIC_RELAXED, __HIP_MEMORY_SCOPE_AGENT);
    __syncthreads();
    if (tid < 8) {
        float v = 0.f;
#pragma unroll
        for (int k = 0; k < 16; ++k) v += s_tmp[tid * 16 + k];
        s_red[tid] = v;
    }
    __syncthreads();
    if (tid == 0) {
        float v = 0.f;
#pragma unroll
        for (int k = 0; k < 8; ++k) v += s_red[k];
        s_h_lds = v;
    }
    __syncthreads();

    // vr[e] = sum_f gh[f] * W[h, f, e0+e]
    {
        int e = tid & 15, fg = tid >> 4;             // 32 groups of 16 f's
        const float* wp = W + (size_t)h * FDIM * FE + (size_t)(fg * 16) * FE + e0 + e;
        float a = 0.f;
#pragma unroll
        for (int k = 0; k < 16; ++k)
            a = fmaf(gh[fg * 16 + k], wp[(size_t)k * FE], a);
        vp[fg][e] = a;
    }
    __syncthreads();
    if (tid < 16) {
        float v = 0.f;
#pragma unroll
        for (int j = 0; j < 32; ++j) v += vp[j][tid];
        vrs[tid] = fmaxf(v / s_h_lds, 0.f);
    }
    __syncthreads();

    // write 512 unique rows x 64 B column chunk
    {
        int row = rc * 512 + tid;
        float4* dst = reinterpret_cast<float4*>(out + (size_t)row * FDIM + h * FE + e0);
        dst[0] = make_float4(vrs[0],  vrs[1],  vrs[2],  vrs[3]);
        dst[1] = make_float4(vrs[4],  vrs[5],  vrs[6],  vrs[7]);
        dst[2] = make_float4(vrs[8],  vrs[9],  vrs[10], vrs[11]);
        dst[3] = make_float4(vrs[12], vrs[13], vrs[14], vrs[15]);
    }
}

extern "C" void kernel_launch(void* const* d_in, const int* in_sizes, int n_in,
                              void* d_out, int out_size, void* d_ws, size_t ws_size,
                              hipStream_t stream) {
    // inputs: 0=X (mathematically unused), 1=G, 2=W, 3=att
    const float* G   = (const float*)d_in[1];
    const float* W   = (const float*)d_in[2];
    const float* att = (const float*)d_in[3];
    float* out = (float*)d_out;
    float* ws  = (float*)d_ws;

    k_init <<<64,   256,  0, stream>>>(W, att, ws);
    k_fused<<<NBLK, NTHR, 0, stream>>>(G, W, ws, out);
}

// Round 10
// 39.563 us; speedup vs baseline: 1.1103x; 1.1103x over previous
//
#include <hip/hip_runtime.h>

// B=2048, N=8192, F=512, H=8, F_=64
// Identity: softmax_n(e1[b]+e2[n]) == softmax_n(e2[n]) => output independent of b.
// Deferred normalization (softmax shift-invariant; e2 ~ N(0,0.45), exp safe):
//   w2[h] = W[h]@a2[h];  g[h] = sum_n exp(G[n].w2[h]) G[n];  s[h] = sum_n exp(...)
//   out[b,:] = relu((g[h]/s[h]) @ W[h])   broadcast over b.
//
// Rounds 5-9 lesson: ANY bulk data movement through agent-scope atomics
// (RMW adds, atomic stores, atomic loads) is uncached memory-side traffic
// => ~30-40us floor regardless of sync mechanism. Rounds 1-4 proved the
// boundary-synced path (normal stores -> kernel boundary -> normal loads)
// is correct and fast. So: 3 plain kernels, ZERO atomics, all cached access.
//   k_w2    256 blk : w2 = W@a2 (16 lanes per output, coalesced 8MB W read)
//   k_gpass 128x512 : G pass -> 128 per-block partials (g 4096, s 8), plain stores
//   k_vr    128x512 : float4 cached reduce of partials + distributed vr slice
//                     + 4MB broadcast write

#define HF   8
#define FDIM 512
#define FE   64
#define NG   8192
#define BX   2048
#define NBLK 128
#define NTHR 512
#define ROWSPB (NG / NBLK)    // 64 rows of G per block, 8 per wave

// ws float layout: [0..4096)=w2 | [4096..5120)=s_part[128][8] | [8192..)=part[128][4096]
#define WS_SP   4096
#define WS_PART 8192

__global__ __launch_bounds__(256) void k_w2(const float* __restrict__ W,
                                            const float* __restrict__ att,
                                            float* __restrict__ w2) {
    int o = blockIdx.x * 16 + (threadIdx.x >> 4);   // 0..4095 (o = h*512 + f)
    int sub = threadIdx.x & 15;
    int h = o >> 9;
    float4 w4 = *reinterpret_cast<const float4*>(W + (size_t)o * FE + sub * 4);
    const float* a2 = att + h * (2 * FE) + FE + sub * 4;
    float s = w4.x * a2[0] + w4.y * a2[1] + w4.z * a2[2] + w4.w * a2[3];
    s += __shfl_xor(s, 1, 64);
    s += __shfl_xor(s, 2, 64);
    s += __shfl_xor(s, 4, 64);
    s += __shfl_xor(s, 8, 64);
    if (sub == 0) w2[o] = s;
}

__global__ __launch_bounds__(NTHR, 1) void k_gpass(const float* __restrict__ G,
                                                   const float* __restrict__ w2g,
                                                   float* __restrict__ ws) {
    __shared__ float lds2[2][HF * FDIM];           // 32 KiB combine buffers
    __shared__ float s_lds[8][HF];

    int bid = blockIdx.x, tid = threadIdx.x;
    int wave = tid >> 6, lane = tid & 63;          // 8 waves
    float* s_part = ws + WS_SP;                    // [128][8]
    float* part   = ws + WS_PART;                  // [128][4096]

    float4 w2a[HF], w2b[HF];
#pragma unroll
    for (int h = 0; h < HF; ++h) {
        const float* wp = w2g + h * FDIM + lane * 8;
        w2a[h] = *reinterpret_cast<const float4*>(wp);
        w2b[h] = *reinterpret_cast<const float4*>(wp + 4);
    }
    float4 accA[HF], accB[HF];
#pragma unroll
    for (int h = 0; h < HF; ++h) {
        accA[h] = make_float4(0.f, 0.f, 0.f, 0.f);
        accB[h] = make_float4(0.f, 0.f, 0.f, 0.f);
    }
    float s_acc[HF] = {};

    int n0 = bid * ROWSPB + wave * (ROWSPB / 8);
    for (int r = 0; r < ROWSPB / 8; ++r) {
        const float* gp = G + (size_t)(n0 + r) * FDIM + lane * 8;
        float4 g0 = *reinterpret_cast<const float4*>(gp);
        float4 g1 = *reinterpret_cast<const float4*>(gp + 4);
        float e[HF];
#pragma unroll
        for (int h = 0; h < HF; ++h)
            e[h] = g0.x * w2a[h].x + g0.y * w2a[h].y + g0.z * w2a[h].z + g0.w * w2a[h].w
                 + g1.x * w2b[h].x + g1.y * w2b[h].y + g1.z * w2b[h].z + g1.w * w2b[h].w;
#pragma unroll
        for (int off = 32; off > 0; off >>= 1) {
#pragma unroll
            for (int h = 0; h < HF; ++h) e[h] += __shfl_xor(e[h], off, 64);
        }
#pragma unroll
        for (int h = 0; h < HF; ++h) {
            float w = __expf(e[h]);                // identical across lanes
            s_acc[h] += w;
            accA[h].x = fmaf(w, g0.x, accA[h].x);
            accA[h].y = fmaf(w, g0.y, accA[h].y);
            accA[h].z = fmaf(w, g0.z, accA[h].z);
            accA[h].w = fmaf(w, g0.w, accA[h].w);
            accB[h].x = fmaf(w, g1.x, accB[h].x);
            accB[h].y = fmaf(w, g1.y, accB[h].y);
            accB[h].z = fmaf(w, g1.z, accB[h].z);
            accB[h].w = fmaf(w, g1.w, accB[h].w);
        }
    }

    if (lane == 0) {
#pragma unroll
        for (int h = 0; h < HF; ++h) s_lds[wave][h] = s_acc[h];
    }

    // 8-wave combine into 2 LDS buffers (pairs in fixed order => deterministic)
    for (int rnd = 0; rnd < 4; ++rnd) {
        if ((wave >> 1) == rnd) {
            int buf = wave & 1;
#pragma unroll
            for (int h = 0; h < HF; ++h) {
                float* dst = lds2[buf] + h * FDIM + lane * 8;
                if (rnd == 0) {
                    *reinterpret_cast<float4*>(dst)     = accA[h];
                    *reinterpret_cast<float4*>(dst + 4) = accB[h];
                } else {
                    float4 t0 = *reinterpret_cast<float4*>(dst);
                    float4 t1 = *reinterpret_cast<float4*>(dst + 4);
                    t0.x += accA[h].x; t0.y += accA[h].y; t0.z += accA[h].z; t0.w += accA[h].w;
                    t1.x += accB[h].x; t1.y += accB[h].y; t1.z += accB[h].z; t1.w += accB[h].w;
                    *reinterpret_cast<float4*>(dst)     = t0;
                    *reinterpret_cast<float4*>(dst + 4) = t1;
                }
            }
        }
        __syncthreads();
    }

    // publish per-block partial with PLAIN float4 stores (cached; kernel-end
    // release makes them visible to the next dispatch)
    {
        float4* pdst = reinterpret_cast<float4*>(part + (size_t)bid * (HF * FDIM));
        const float4* a = reinterpret_cast<const float4*>(lds2[0]);
        const float4* b = reinterpret_cast<const float4*>(lds2[1]);
        for (int i = tid; i < HF * FDIM / 4; i += NTHR) {
            float4 x = a[i], y = b[i];
            x.x += y.x; x.y += y.y; x.z += y.z; x.w += y.w;
            pdst[i] = x;
        }
        if (tid < HF) {
            float sv = 0.f;
#pragma unroll
            for (int w = 0; w < 8; ++w) sv += s_lds[w][tid];
            s_part[bid * HF + tid] = sv;
        }
    }
}

__global__ __launch_bounds__(NTHR, 1) void k_vr(const float* __restrict__ W,
                                                const float* __restrict__ ws,
                                                float* __restrict__ out) {
    __shared__ float4 red4[4][128];                // 8 KiB
    __shared__ float gh[FDIM];
    __shared__ float vp[32][17];
    __shared__ float vrs[16];
    __shared__ float s_tmp[128];
    __shared__ float s_h_lds;

    int bid = blockIdx.x, tid = threadIdx.x;
    const float* s_part = ws + WS_SP;              // [128][8]
    const float* part   = ws + WS_PART;            // [128][4096]

    // 128 blocks = 32 column-slices (h, 16 e's) x 4 row-chunks of 512 rows
    int slice = bid & 31, rc = bid >> 5;
    int h = slice >> 2, e0 = (slice & 3) * 16;

    // gh[f] = sum over 128 partials; float4 cached loads, 4 p-groups of 32
    {
        int fq = tid & 127, pg = tid >> 7;         // fq: float4 col, pg: 0..3
        const float4* pcol = reinterpret_cast<const float4*>(part + (size_t)h * FDIM) + fq;
        float4 a = make_float4(0.f, 0.f, 0.f, 0.f);
#pragma unroll 8
        for (int p = 0; p < 32; ++p) {
            float4 v = pcol[(size_t)(pg * 32 + p) * (HF * FDIM / 4)];
            a.x += v.x; a.y += v.y; a.z += v.z; a.w += v.w;
        }
        red4[pg][fq] = a;
    }
    if (tid >= 256 && tid < 384)
        s_tmp[tid - 256] = s_part[(tid - 256) * HF + h];
    __syncthreads();
    if (tid < 128) {
        float4 a = red4[0][tid], b = red4[1][tid], c = red4[2][tid], d = red4[3][tid];
        float4 r = make_float4((a.x + b.x) + (c.x + d.x), (a.y + b.y) + (c.y + d.y),
                               (a.z + b.z) + (c.z + d.z), (a.w + b.w) + (c.w + d.w));
        reinterpret_cast<float4*>(gh)[tid] = r;
    }
    if (tid == 0) {
        float v = 0.f;
        for (int k = 0; k < 128; ++k) v += s_tmp[k];
        s_h_lds = v;
    }
    __syncthreads();

    // vr[e] = sum_f gh[f] * W[h, f, e0+e]
    {
        int e = tid & 15, fg = tid >> 4;           // 32 groups of 16 f's
        const float* wp = W + (size_t)h * FDIM * FE + (size_t)(fg * 16) * FE + e0 + e;
        float a = 0.f;
#pragma unroll
        for (int k = 0; k < 16; ++k)
            a = fmaf(gh[fg * 16 + k], wp[(size_t)k * FE], a);
        vp[fg][e] = a;
    }
    __syncthreads();
    if (tid < 16) {
        float v = 0.f;
#pragma unroll
        for (int j = 0; j < 32; ++j) v += vp[j][tid];
        vrs[tid] = fmaxf(v / s_h_lds, 0.f);
    }
    __syncthreads();

    // write 512 unique rows x 64 B column chunk (each thread one full 64B line)
    {
        int row = rc * 512 + tid;
        float4* dst = reinterpret_cast<float4*>(out + (size_t)row * FDIM + h * FE + e0);
        dst[0] = make_float4(vrs[0],  vrs[1],  vrs[2],  vrs[3]);
        dst[1] = make_float4(vrs[4],  vrs[5],  vrs[6],  vrs[7]);
        dst[2] = make_float4(vrs[8],  vrs[9],  vrs[10], vrs[11]);
        dst[3] = make_float4(vrs[12], vrs[13], vrs[14], vrs[15]);
    }
}

extern "C" void kernel_launch(void* const* d_in, const int* in_sizes, int n_in,
                              void* d_out, int out_size, void* d_ws, size_t ws_size,
                              hipStream_t stream) {
    // inputs: 0=X (mathematically unused), 1=G, 2=W, 3=att
    const float* G   = (const float*)d_in[1];
    const float* W   = (const float*)d_in[2];
    const float* att = (const float*)d_in[3];
    float* out = (float*)d_out;
    float* ws  = (float*)d_ws;

    k_w2   <<<256,  256,  0, stream>>>(W, att, ws);
    k_gpass<<<NBLK, NTHR, 0, stream>>>(G, ws, ws);
    k_vr   <<<NBLK, NTHR, 0, stream>>>(W, ws, out);
}